// Round 1
// baseline (11250.240 us; speedup 1.0000x reference)
//
#include <hip/hip_runtime.h>
#include <cstdint>
#include <cstddef>

#define HID 1024
#define INP 512
#define BATCH 128
#define TSTEPS 256
#define NK16 96         // K/16 total (x: 0..31, h: 32..95)
#define ZSLOTS 32       // rotating z0 chunk depth (t mod 32)
#define NBLK_CHUNK 256  // persistent-chunk grid size (must all be co-resident)

using short8  = __attribute__((ext_vector_type(8))) short;
using f32x16  = __attribute__((ext_vector_type(16))) float;

#define LD8(p) (*(const short8*)(p))
#define MFMA32(a,b,c) __builtin_amdgcn_mfma_f32_32x32x16_bf16((a),(b),(c),0,0,0)

static __device__ __forceinline__ unsigned short f2bf(float f) {
    union { float f; unsigned int u; } v; v.f = f;
    unsigned int r = v.u + 0x7fffu + ((v.u >> 16) & 1u);   // RNE
    return (unsigned short)(r >> 16);
}
static __device__ __forceinline__ float bf2f(unsigned short b) {
    union { unsigned int u; float f; } v; v.u = ((unsigned int)b) << 16;
    return v.f;
}
static __device__ __forceinline__ float sigmoid_f(float z) {
    return 1.0f / (1.0f + __expf(-z));
}
static __device__ __forceinline__ float tanh_f(float z) {
    return 2.0f / (1.0f + __expf(-2.0f * z)) - 1.0f;
}

// ---------------------------------------------------------------------------
// Fragment layouts (32x32x16 MFMA; verified rounds 4-7):
//   A: lane l holds W[s*32 + (l&31)][k16*16 + (l>>5)*8 + e]
//      wfrag[s:128][k16:96][p:2][lane:64][e:8]   (p: 0=hi, 1=lo)
//   B: lane l holds act[col = cg*32 + (l&31)][k16*16 + (l>>5)*8 + e]
//      xfrag[t:256][k16:32][cg:4][p:2][lane:64][e:8]
//      hfrag[k16:64][cg:4][p:2][lane:64][e:8]
//   z0[tslot:32][s:128][lr:32][col:128] f32, lr = gate-row within slice.
// ---------------------------------------------------------------------------

// Prep 1: weights -> wfrag. Grid (96, 128) = (k16, s), 256 threads.
__global__ void prep_w(const float* __restrict__ Wgx, const float* __restrict__ Wix,
                       const float* __restrict__ Wfx, const float* __restrict__ Wox,
                       const float* __restrict__ Wgh, const float* __restrict__ Wih,
                       const float* __restrict__ Wfh, const float* __restrict__ Woh,
                       unsigned short* __restrict__ wfrag)
{
    const int k16 = blockIdx.x;        // 0..95
    const int s   = blockIdx.y;        // 0..127
    const int tid  = threadIdx.x;
    const int lane = tid >> 2;         // 0..63
    const int e0   = (tid & 3) * 2;    // 0,2,4,6
    const int row  = s * 32 + (lane & 31);
    const int k    = k16 * 16 + (lane >> 5) * 8 + e0;
    const int j = row >> 2;
    const int g = row & 3;
    float f0, f1;
    if (k < INP) {
        const float* wx = (g == 0 ? Wgx : g == 1 ? Wix : g == 2 ? Wfx : Wox) + (size_t)j * INP;
        f0 = wx[k]; f1 = wx[k + 1];
    } else {
        const float* wh = (g == 0 ? Wgh : g == 1 ? Wih : g == 2 ? Wfh : Woh) + (size_t)j * HID;
        f0 = wh[k - INP]; f1 = wh[k - INP + 1];
    }
    ushort2 hi, lo;
    hi.x = f2bf(f0); lo.x = f2bf(f0 - bf2f(hi.x));
    hi.y = f2bf(f1); lo.y = f2bf(f1 - bf2f(hi.y));
    unsigned short* base = wfrag + ((size_t)(s * NK16 + k16) * 2) * 512 + lane * 8 + e0;
    *(ushort2*)(base)       = hi;
    *(ushort2*)(base + 512) = lo;
}

// Prep 2: x -> xfrag. Grid (32, 256) = (k16x, t), 256 threads.
__global__ void prep_x(const float* __restrict__ x, unsigned short* __restrict__ xfrag)
{
    const int k16x = blockIdx.x;       // 0..31
    const int t    = blockIdx.y;       // 0..255
    const int tid  = threadIdx.x;
    const int cg   = tid >> 6;         // 0..3
    const int lane = tid & 63;
    const int col  = cg * 32 + (lane & 31);
    const int k0   = k16x * 16 + (lane >> 5) * 8;
    const float* src = x + ((size_t)col * TSTEPS + t) * INP + k0;
    const float4 v0 = *(const float4*)(src);
    const float4 v1 = *(const float4*)(src + 4);
    ushort4 h0, l0, h1, l1;
    h0.x = f2bf(v0.x); l0.x = f2bf(v0.x - bf2f(h0.x));
    h0.y = f2bf(v0.y); l0.y = f2bf(v0.y - bf2f(h0.y));
    h0.z = f2bf(v0.z); l0.z = f2bf(v0.z - bf2f(h0.z));
    h0.w = f2bf(v0.w); l0.w = f2bf(v0.w - bf2f(h0.w));
    h1.x = f2bf(v1.x); l1.x = f2bf(v1.x - bf2f(h1.x));
    h1.y = f2bf(v1.y); l1.y = f2bf(v1.y - bf2f(h1.y));
    h1.z = f2bf(v1.z); l1.z = f2bf(v1.z - bf2f(h1.z));
    h1.w = f2bf(v1.w); l1.w = f2bf(v1.w - bf2f(h1.w));
    unsigned short* base = xfrag +
        ((size_t)(((size_t)t * 32 + k16x) * 4 + cg) * 2) * 512 + lane * 8;
    *(ushort4*)(base)           = h0;
    *(ushort4*)(base + 4)       = h1;
    *(ushort4*)(base + 512)     = l0;
    *(ushort4*)(base + 512 + 4) = l1;
}

// Prep 3: c copy; h0 (H,B) -> hfrag0; zero the grid-barrier words. 512x256.
__global__ void prep_state(const float* __restrict__ cin, const float* __restrict__ hin,
                           float* __restrict__ cdst, unsigned short* __restrict__ hfrag0,
                           unsigned* __restrict__ bar)
{
    if (blockIdx.x == 0 && threadIdx.x < 64) bar[threadIdx.x] = 0u;
    const int idx = blockIdx.x * 256 + threadIdx.x;   // 0..131071
    cdst[idx] = cin[idx];
    const int j = idx >> 7;
    const int b = idx & 127;
    float f = hin[idx];
    unsigned short hh = f2bf(f);
    unsigned short hl = f2bf(f - bf2f(hh));
    const int k16h = j >> 4;
    const int hlf  = (j >> 3) & 1;
    const int e    = j & 7;
    const int cg   = b >> 5;
    const int lane = 32 * hlf + (b & 31);
    unsigned short* base = hfrag0 +
        ((size_t)((k16h * 4 + cg) * 2) * 512) + lane * 8 + e;
    base[0]   = hh;
    base[512] = hl;
}

// ---------------------------------------------------------------------------
// z0 chunk GEMM: z0[t][.] = Wx . x_t + b for t in [tbase, tbase+32).
// Grid (s:128, tq:32) x 512 thr. Block: 32 gate-rows x 128 cols, K=512.
// (unchanged from previous round)
// ---------------------------------------------------------------------------
__global__ __launch_bounds__(512, 2) void gemm_z0(
    const unsigned short* __restrict__ wfrag,
    const unsigned short* __restrict__ xfrag,
    float* __restrict__ z0,
    const float* __restrict__ bg, const float* __restrict__ bi,
    const float* __restrict__ bf_, const float* __restrict__ bo,
    int tbase)
{
    const int tid  = threadIdx.x;
    const int wv   = tid >> 6;
    const int lane = tid & 63;
    const int l31  = lane & 31;
    const int hl   = lane >> 5;
    const int cw   = wv & 1;
    const int kq   = wv >> 1;              // 0..3
    const int s    = blockIdx.x;           // 0..127
    const int t    = tbase + blockIdx.y;   // timestep
    const int tslot = t & (ZSLOTS - 1);

    const unsigned short* pA = wfrag + ((size_t)(s * NK16 + kq) * 2) * 512 + lane * 8;
    const unsigned short* pB = xfrag + (size_t)t * 131072
                             + (size_t)(4 * kq + 2 * cw) * 1024 + lane * 8;

    f32x16 a0A, a0B, a1A, a1B;
#pragma unroll
    for (int r = 0; r < 16; ++r) { a0A[r]=0.f; a0B[r]=0.f; a1A[r]=0.f; a1B[r]=0.f; }

#pragma unroll
    for (int m = 0; m < 8; ++m) {
        short8 Ah  = LD8(pA);
        short8 Al  = LD8(pA + 512);
        short8 B0h = LD8(pB);
        short8 B0l = LD8(pB + 512);
        short8 B1h = LD8(pB + 1024);
        short8 B1l = LD8(pB + 1536);
        pA += 4096; pB += 16384;
        a0A = MFMA32(Ah, B0h, a0A);
        a1A = MFMA32(Ah, B1h, a1A);
        a0B = MFMA32(Ah, B0l, a0B);
        a1B = MFMA32(Ah, B1l, a1B);
        a0A = MFMA32(Al, B0h, a0A);
        a1A = MFMA32(Al, B1h, a1A);
    }

    __shared__ float part[2][32][128];     // 32 KB

    if (kq >= 2) {
#pragma unroll
        for (int r = 0; r < 16; ++r) {
            const int lr = (r & 3) + 8 * (r >> 2) + 4 * hl;
            part[kq - 2][lr][(2 * cw)     * 32 + l31] = a0A[r] + a0B[r];
            part[kq - 2][lr][(2 * cw + 1) * 32 + l31] = a1A[r] + a1B[r];
        }
    }
    __syncthreads();
    if (kq < 2) {
#pragma unroll
        for (int r = 0; r < 16; ++r) {
            const int lr = (r & 3) + 8 * (r >> 2) + 4 * hl;
            part[kq][lr][(2 * cw)     * 32 + l31] += a0A[r] + a0B[r];
            part[kq][lr][(2 * cw + 1) * 32 + l31] += a1A[r] + a1B[r];
        }
    }
    __syncthreads();

    {
        const int lr = tid >> 4;
        const int c0 = (tid & 15) * 8;
        const int g  = lr & 3;
        const int j  = s * 8 + (lr >> 2);
        const float bb = (g == 0 ? bg : g == 1 ? bi : g == 2 ? bf_ : bo)[j];
        float z[8];
#pragma unroll
        for (int cc = 0; cc < 8; ++cc)
            z[cc] = part[0][lr][c0 + cc] + part[1][lr][c0 + cc] + bb;
        float* dst = z0 + (((size_t)tslot * 128 + s) * 32 + lr) * 128 + c0;
        *(float4*)(dst)     = make_float4(z[0], z[1], z[2], z[3]);
        *(float4*)(dst + 4) = make_float4(z[4], z[5], z[6], z[7]);
    }
}

// ---------------------------------------------------------------------------
// Device-wide sense-reversing barrier (agent scope).
// Pattern is identical to cooperative-groups grid.sync():
//   __syncthreads (all waves' stores drained to L2 via vmcnt(0) at s_barrier)
//   thread0: release fence (wbL2) -> arrive -> spin on generation -> acquire
//   fence (invL1/L2 so remote h writes are visible) -> __syncthreads.
// bar[0] = arrival counter, bar[1] = generation.
// ---------------------------------------------------------------------------
static __device__ __forceinline__ void grid_barrier(unsigned* __restrict__ bar)
{
    __syncthreads();
    if (threadIdx.x == 0) {
        __threadfence();   // release: our block's h stores L2 -> coherence point
        unsigned g = __hip_atomic_load(&bar[1], __ATOMIC_RELAXED,
                                       __HIP_MEMORY_SCOPE_AGENT);
        unsigned a = __hip_atomic_fetch_add(&bar[0], 1u, __ATOMIC_ACQ_REL,
                                            __HIP_MEMORY_SCOPE_AGENT);
        if (a == (unsigned)(NBLK_CHUNK - 1)) {
            __hip_atomic_store(&bar[0], 0u, __ATOMIC_RELAXED,
                               __HIP_MEMORY_SCOPE_AGENT);
            __hip_atomic_store(&bar[1], g + 1u, __ATOMIC_RELEASE,
                               __HIP_MEMORY_SCOPE_AGENT);
        } else {
            while (__hip_atomic_load(&bar[1], __ATOMIC_RELAXED,
                                     __HIP_MEMORY_SCOPE_AGENT) == g)
                __builtin_amdgcn_s_sleep(2);
        }
        __threadfence();   // acquire: invalidate L1/L2 so remote h is visible
    }
    __syncthreads();
}

// ---------------------------------------------------------------------------
// Persistent chunk: 32 LSTM timesteps in ONE launch with internal grid
// barriers. Per-block W h-slice pinned in 64 VGPRs (loaded once per chunk,
// survives the per-step L2 invalidates), c in a register, z0 adds for step
// t+1 prefetched before the barrier so their L3 latency hides under the wait.
// Grid 256 x 512 thr, LDS 64 KB, VGPR<=256: worst-case packing is 2 blk/CU
// capacity with 256 blocks <= 256 CUs -> all blocks always resident, barrier
// cannot deadlock. Double-buffered h + one barrier/step is race-free.
// ---------------------------------------------------------------------------
__global__ __launch_bounds__(512, 1) void lstm_chunk(
    const unsigned short* __restrict__ wfrag,
    const float* __restrict__ z0,
    unsigned short* __restrict__ hf0,
    unsigned short* __restrict__ hf1,
    float* __restrict__ cst,
    float* __restrict__ outf,
    unsigned* __restrict__ bar,
    int tbase)
{
    const int tid  = threadIdx.x;
    const int wv   = tid >> 6;             // K-slice 0..7
    const int lane = tid & 63;
    const int l31  = lane & 31;
    const int hl   = lane >> 5;
    const int bx   = blockIdx.x;

    const int xcd     = bx & 7;
    const int ii      = bx >> 3;
    const int s       = xcd * 16 + (ii >> 1);   // rowslice 0..127
    const int cb      = ii & 1;                 // col half
    const int colbase = cb << 6;
    const int J0      = s * 8;

    // epilogue role: thread = (jloc = tid>>6, cl = tid&63)
    const int ejl  = tid >> 6;
    const int ecl  = tid & 63;
    const int ej   = J0 + ejl;
    const int ecol = colbase + ecl;
    const size_t ci = (size_t)ej * BATCH + ecol;

    // W h-part -> registers (16 x short8 = 64 VGPRs), once per chunk.
    short8 WAh[8], WAl[8];
    {
        const unsigned short* pA = wfrag +
            ((size_t)(s * NK16 + 32 + wv) * 2) * 512 + lane * 8;
#pragma unroll
        for (int m = 0; m < 8; ++m) {
            WAh[m] = LD8(pA);
            WAl[m] = LD8(pA + 512);
            pA += 8192;
        }
    }
    float creg = cst[ci];                    // c lives in a register all chunk
    const size_t bOff = (size_t)(4 * wv + 2 * cb) * 1024 + lane * 8;

    // h-scatter address (fragment layout) is time-invariant; precompute.
    const int k16h  = s >> 1;
    const int cgg   = (colbase >> 5) + (ecl >> 5);
    const int lane8 = 32 * (s & 1) + (ecl & 31);
    const size_t hscat = ((size_t)((k16h * 4 + cgg) * 2) * 512) + lane8 * 8 + ejl;

    __shared__ float part[8][32][64];        // 64 KB

    // z0 preload for first step of the chunk
    float nadd0, nadd1, nadd2, nadd3;
    {
        const float* zp = z0 + (((size_t)(tbase & (ZSLOTS - 1)) * 128 + s) * 32
                                + 4 * ejl) * 128 + ecol;
        nadd0 = zp[0]; nadd1 = zp[128]; nadd2 = zp[256]; nadd3 = zp[384];
    }

#pragma unroll 1
    for (int tt = 0; tt < ZSLOTS; ++tt) {
        const int t = tbase + tt;
        const unsigned short* hin  = (t & 1) ? hf1 : hf0;
        unsigned short*       hout = (t & 1) ? hf0 : hf1;
        const float add0 = nadd0, add1 = nadd1, add2 = nadd2, add3 = nadd3;

        f32x16 a0A, a0B, a1A, a1B;
#pragma unroll
        for (int r = 0; r < 16; ++r) { a0A[r]=0.f; a0B[r]=0.f; a1A[r]=0.f; a1B[r]=0.f; }

        // h-only K-loop: k16h = 8m + wv, W from registers, 4 loads + 6 MFMAs.
        const unsigned short* pH = hin + bOff;
#pragma unroll
        for (int m = 0; m < 8; ++m) {
            short8 B0h = LD8(pH);
            short8 B0l = LD8(pH + 512);
            short8 B1h = LD8(pH + 1024);
            short8 B1l = LD8(pH + 1536);
            pH += 32768;
            a0A = MFMA32(WAh[m], B0h, a0A);
            a1A = MFMA32(WAh[m], B1h, a1A);
            a0B = MFMA32(WAh[m], B0l, a0B);
            a1B = MFMA32(WAh[m], B1l, a1B);
            a0A = MFMA32(WAl[m], B0h, a0A);
            a1A = MFMA32(WAl[m], B1h, a1A);
        }

        // single-stage K-partial dump: all 8 waves, one barrier.
#pragma unroll
        for (int r = 0; r < 16; ++r) {
            const int lr = (r & 3) + 8 * (r >> 2) + 4 * hl;
            part[wv][lr][l31]      = a0A[r] + a0B[r];
            part[wv][lr][32 + l31] = a1A[r] + a1B[r];
        }
        __syncthreads();

        // gates: thread (ejl, ecl); sum 8 K-partials per gate.
        {
            const int r0 = 4 * ejl;
            float z0g = add0, z1g = add1, z2g = add2, z3g = add3;
#pragma unroll
            for (int p = 0; p < 8; ++p) {
                z0g += part[p][r0 + 0][ecl];
                z1g += part[p][r0 + 1][ecl];
                z2g += part[p][r0 + 2][ecl];
                z3g += part[p][r0 + 3][ecl];
            }
            float gg = tanh_f(z0g);
            float ig = sigmoid_f(z1g);
            float fg = sigmoid_f(z2g);
            float og = sigmoid_f(z3g);
            float cn = gg * ig + creg * fg;
            creg = cn;
            float hh = tanh_f(cn) * og;
            unsigned short hb  = f2bf(hh);
            unsigned short hlo = f2bf(hh - bf2f(hb));
            hout[hscat]       = hb;
            hout[hscat + 512] = hlo;
            if (outf && t == TSTEPS - 1) outf[ci] = hh;
        }

        if (tt + 1 < ZSLOTS) {
            // prefetch next step's z0 adds BEFORE the barrier (z0 is const
            // this launch) - L3 latency hides under the barrier wait.
            const float* zn = z0 + (((size_t)((t + 1) & (ZSLOTS - 1)) * 128 + s) * 32
                                    + 4 * ejl) * 128 + ecol;
            nadd0 = zn[0]; nadd1 = zn[128]; nadd2 = zn[256]; nadd3 = zn[384];
            grid_barrier(bar);
        }
    }
    cst[ci] = creg;
}

// ---------------------------------------------------------------------------
// Fallback per-step kernel (used only if ws too small for z0 buffer).
// ---------------------------------------------------------------------------
__global__ __launch_bounds__(512, 1) void lstm_step(
    const unsigned short* __restrict__ wfrag,
    const unsigned short* __restrict__ xfrag,
    const float* __restrict__ z0,
    const unsigned short* __restrict__ hin,
    unsigned short* __restrict__ hout,
    float* __restrict__ cst,
    const float* __restrict__ bg, const float* __restrict__ bi,
    const float* __restrict__ bf_, const float* __restrict__ bo,
    float* __restrict__ outf, int t)
{
    const int tid  = threadIdx.x;
    const int wv   = tid >> 6;
    const int lane = tid & 63;
    const int l31  = lane & 31;
    const int hl   = lane >> 5;
    const int bx   = blockIdx.x;

    const int xcd     = bx & 7;
    const int ii      = bx >> 3;
    const int s       = xcd * 16 + (ii >> 1);
    const int cb      = ii & 1;
    const int colbase = cb << 6;
    const int J0      = s * 8;

    const int ejl  = tid >> 6;
    const int ecl  = tid & 63;
    const int ej   = J0 + ejl;
    const int ecol = colbase + ecl;

    float add0, add1, add2, add3;
    if (z0) {
        const float* zp = z0 + (((size_t)(t & (ZSLOTS - 1)) * 128 + s) * 32
                                + 4 * ejl) * 128 + ecol;
        add0 = zp[0]; add1 = zp[128]; add2 = zp[256]; add3 = zp[384];
    } else {
        add0 = bg[ej]; add1 = bi[ej]; add2 = bf_[ej]; add3 = bo[ej];
    }
    const size_t ci = (size_t)ej * BATCH + ecol;
    float cold = cst[ci];

    f32x16 a0A, a0B, a1A, a1B;
#pragma unroll
    for (int r = 0; r < 16; ++r) { a0A[r]=0.f; a0B[r]=0.f; a1A[r]=0.f; a1B[r]=0.f; }

    const size_t bOff = (size_t)(4 * wv + 2 * cb) * 1024 + lane * 8;

    if (z0) {
        const unsigned short* pA = wfrag + ((size_t)(s * NK16 + 32 + wv) * 2) * 512 + lane * 8;
        const unsigned short* pH = hin + bOff;
#pragma unroll
        for (int m = 0; m < 8; ++m) {
            short8 Ah  = LD8(pA);
            short8 Al  = LD8(pA + 512);
            short8 B0h = LD8(pH);
            short8 B0l = LD8(pH + 512);
            short8 B1h = LD8(pH + 1024);
            short8 B1l = LD8(pH + 1536);
            pA += 8192; pH += 32768;
            a0A = MFMA32(Ah, B0h, a0A);
            a1A = MFMA32(Ah, B1h, a1A);
            a0B = MFMA32(Ah, B0l, a0B);
            a1B = MFMA32(Ah, B1l, a1B);
            a0A = MFMA32(Al, B0h, a0A);
            a1A = MFMA32(Al, B1h, a1A);
        }
    } else {
        const unsigned short* pA = wfrag + ((size_t)(s * NK16 + wv) * 2) * 512 + lane * 8;
        const unsigned short* pX = xfrag + (size_t)t * 131072 + bOff;
#pragma unroll
        for (int m = 0; m < 4; ++m) {
            short8 Ah  = LD8(pA);
            short8 Al  = LD8(pA + 512);
            short8 B0h = LD8(pX);
            short8 B0l = LD8(pX + 512);
            short8 B1h = LD8(pX + 1024);
            short8 B1l = LD8(pX + 1536);
            pA += 8192; pX += 32768;
            a0A = MFMA32(Ah, B0h, a0A);
            a1A = MFMA32(Ah, B1h, a1A);
            a0B = MFMA32(Ah, B0l, a0B);
            a1B = MFMA32(Ah, B1l, a1B);
            a0A = MFMA32(Al, B0h, a0A);
            a1A = MFMA32(Al, B1h, a1A);
        }
        const unsigned short* pH = hin + bOff;
#pragma unroll
        for (int m = 0; m < 8; ++m) {
            short8 Ah  = LD8(pA);
            short8 Al  = LD8(pA + 512);
            short8 B0h = LD8(pH);
            short8 B0l = LD8(pH + 512);
            short8 B1h = LD8(pH + 1024);
            short8 B1l = LD8(pH + 1536);
            pA += 8192; pH += 32768;
            a0A = MFMA32(Ah, B0h, a0A);
            a1A = MFMA32(Ah, B1h, a1A);
            a0B = MFMA32(Ah, B0l, a0B);
            a1B = MFMA32(Ah, B1l, a1B);
            a0A = MFMA32(Al, B0h, a0A);
            a1A = MFMA32(Al, B1h, a1A);
        }
    }

    __shared__ float part[8][32][64];
#pragma unroll
    for (int r = 0; r < 16; ++r) {
        const int lr = (r & 3) + 8 * (r >> 2) + 4 * hl;
        part[wv][lr][l31]      = a0A[r] + a0B[r];
        part[wv][lr][32 + l31] = a1A[r] + a1B[r];
    }
    __syncthreads();

    {
        const int r0 = 4 * ejl;
        float z0g = add0, z1g = add1, z2g = add2, z3g = add3;
#pragma unroll
        for (int p = 0; p < 8; ++p) {
            z0g += part[p][r0 + 0][ecl];
            z1g += part[p][r0 + 1][ecl];
            z2g += part[p][r0 + 2][ecl];
            z3g += part[p][r0 + 3][ecl];
        }
        float gg = tanh_f(z0g);
        float ig = sigmoid_f(z1g);
        float fg = sigmoid_f(z2g);
        float og = sigmoid_f(z3g);
        float cn = gg * ig + cold * fg;
        cst[ci] = cn;
        float hh = tanh_f(cn) * og;
        unsigned short hb  = f2bf(hh);
        unsigned short hlo = f2bf(hh - bf2f(hb));
        const int k16h  = s >> 1;
        const int cgg   = (colbase >> 5) + (ecl >> 5);
        const int lane8 = 32 * (s & 1) + (ecl & 31);
        unsigned short* dst = hout +
            ((size_t)((k16h * 4 + cgg) * 2) * 512) + lane8 * 8 + ejl;
        dst[0]   = hb;
        dst[512] = hlo;
        if (outf) outf[ci] = hh;
    }
}

// ---------------------------------------------------------------------------
extern "C" void kernel_launch(void* const* d_in, const int* in_sizes, int n_in,
                              void* d_out, int out_size, void* d_ws, size_t ws_size,
                              hipStream_t stream)
{
    const float* x   = (const float*)d_in[0];
    const float* c0v = (const float*)d_in[1];
    const float* h0v = (const float*)d_in[2];
    const float* Wgx = (const float*)d_in[3];
    const float* Wix = (const float*)d_in[4];
    const float* Wfx = (const float*)d_in[5];
    const float* Wox = (const float*)d_in[6];
    const float* Wgh = (const float*)d_in[7];
    const float* Wih = (const float*)d_in[8];
    const float* Wfh = (const float*)d_in[9];
    const float* Woh = (const float*)d_in[10];
    const float* bg  = (const float*)d_in[11];
    const float* bi  = (const float*)d_in[12];
    const float* bf  = (const float*)d_in[13];
    const float* bo  = (const float*)d_in[14];

    // ws layout (ushort unless noted):
    //   wfrag 25.2 MB | xfrag 67.1 MB | hf0,hf1 0.5 MB ea | cst 0.5 MB
    //   z0 64 MB (f32) | bar 256 B  => mode-A total ~161 MB
    unsigned short* wfrag = (unsigned short*)d_ws;
    unsigned short* xfrag = wfrag + (size_t)128 * NK16 * 2 * 512;
    unsigned short* hf0   = xfrag + (size_t)TSTEPS * 32 * 4 * 2 * 512;
    unsigned short* hf1   = hf0 + (size_t)64 * 4 * 2 * 512;
    float* cst            = (float*)(hf1 + (size_t)64 * 4 * 2 * 512);
    float* z0             = (float*)(cst + (size_t)HID * BATCH);
    unsigned* bar         = (unsigned*)(z0 + (size_t)ZSLOTS * 4096 * 128);

    const size_t needA = (size_t)((char*)(bar + 64) - (char*)d_ws);
    const bool useA = (ws_size >= needA);

    unsigned short* hf[2] = { hf0, hf1 };
    float* outp = (float*)d_out;

    prep_w<<<dim3(NK16, 128), dim3(256), 0, stream>>>(Wgx, Wix, Wfx, Wox,
                                                      Wgh, Wih, Wfh, Woh, wfrag);
    prep_x<<<dim3(32, TSTEPS), dim3(256), 0, stream>>>(x, xfrag);
    prep_state<<<dim3(512), dim3(256), 0, stream>>>(c0v, h0v, cst, hf[0], bar);

    if (useA) {
        for (int q = 0; q < TSTEPS / ZSLOTS; ++q) {
            gemm_z0<<<dim3(128, ZSLOTS), dim3(512), 0, stream>>>(
                wfrag, xfrag, z0, bg, bi, bf, bo, q * ZSLOTS);
            lstm_chunk<<<dim3(NBLK_CHUNK), dim3(512), 0, stream>>>(
                wfrag, z0, hf0, hf1, cst, outp, bar, q * ZSLOTS);
        }
    } else {
        for (int t = 0; t < TSTEPS; ++t) {
            lstm_step<<<dim3(256), dim3(512), 0, stream>>>(
                wfrag, xfrag, nullptr, hf[t & 1], hf[(t + 1) & 1],
                cst, bg, bi, bf, bo,
                (t == TSTEPS - 1) ? outp : nullptr, t);
        }
    }
}

// Round 2
// 4011.662 us; speedup vs baseline: 2.8044x; 2.8044x over previous
//
#include <hip/hip_runtime.h>
#include <cstdint>
#include <cstddef>

#define HID 1024
#define INP 512
#define BATCH 128
#define TSTEPS 256
#define NK16 96         // K/16 total (x: 0..31, h: 32..95)
#define ZSLOTS 16       // chunk depth AND h/z0 slot rotation depth
#define NBLK_CHUNK 256  // persistent-chunk grid size (must all be co-resident)
#define HSLOT ((size_t)64 * 4 * 2 * 512)   // ushorts per h slot (0.5 MB)

using short8  = __attribute__((ext_vector_type(8))) short;
using f32x16  = __attribute__((ext_vector_type(16))) float;

#define LD8(p) (*(const short8*)(p))
#define MFMA32(a,b,c) __builtin_amdgcn_mfma_f32_32x32x16_bf16((a),(b),(c),0,0,0)

static __device__ __forceinline__ unsigned short f2bf(float f) {
    union { float f; unsigned int u; } v; v.f = f;
    unsigned int r = v.u + 0x7fffu + ((v.u >> 16) & 1u);   // RNE
    return (unsigned short)(r >> 16);
}
static __device__ __forceinline__ float bf2f(unsigned short b) {
    union { unsigned int u; float f; } v; v.u = ((unsigned int)b) << 16;
    return v.f;
}
static __device__ __forceinline__ float sigmoid_f(float z) {
    return 1.0f / (1.0f + __expf(-z));
}
static __device__ __forceinline__ float tanh_f(float z) {
    return 2.0f / (1.0f + __expf(-2.0f * z)) - 1.0f;
}

// ---------------------------------------------------------------------------
// Fragment layouts (32x32x16 MFMA; verified):
//   A: lane l holds W[s*32 + (l&31)][k16*16 + (l>>5)*8 + e]
//      wfrag[s:128][k16:96][p:2][lane:64][e:8]   (p: 0=hi, 1=lo)
//   B: lane l holds act[col = cg*32 + (l&31)][k16*16 + (l>>5)*8 + e]
//      xfrag[t:256][k16:32][cg:4][p:2][lane:64][e:8]
//      hbuf[slot:16][k16:64][cg:4][p:2][lane:64][e:8]   (rotating slots)
//   z0[tslot:16][s:128][lr:32][col:128] f32, lr = gate-row within slice.
//
// Cross-block h transport (fence-free): producers write h into slot (t&15)
// with agent-scope relaxed atomic u64 stores (sc1 -> write-through to MALL,
// bypassing all L2s). Readers use plain cached loads: slot addresses are
// fresh each step within a chunk (16 slots, 16 steps), so every L2 read is
// a cold miss that fetches the up-to-date MALL data. No wbl2/inv anywhere.
// Cross-chunk slot reuse is safe: kernel-boundary acquire invalidates L2.
// ---------------------------------------------------------------------------

// Prep 1: weights -> wfrag. Grid (96, 128) = (k16, s), 256 threads.
__global__ void prep_w(const float* __restrict__ Wgx, const float* __restrict__ Wix,
                       const float* __restrict__ Wfx, const float* __restrict__ Wox,
                       const float* __restrict__ Wgh, const float* __restrict__ Wih,
                       const float* __restrict__ Wfh, const float* __restrict__ Woh,
                       unsigned short* __restrict__ wfrag)
{
    const int k16 = blockIdx.x;        // 0..95
    const int s   = blockIdx.y;        // 0..127
    const int tid  = threadIdx.x;
    const int lane = tid >> 2;         // 0..63
    const int e0   = (tid & 3) * 2;    // 0,2,4,6
    const int row  = s * 32 + (lane & 31);
    const int k    = k16 * 16 + (lane >> 5) * 8 + e0;
    const int j = row >> 2;
    const int g = row & 3;
    float f0, f1;
    if (k < INP) {
        const float* wx = (g == 0 ? Wgx : g == 1 ? Wix : g == 2 ? Wfx : Wox) + (size_t)j * INP;
        f0 = wx[k]; f1 = wx[k + 1];
    } else {
        const float* wh = (g == 0 ? Wgh : g == 1 ? Wih : g == 2 ? Wfh : Woh) + (size_t)j * HID;
        f0 = wh[k - INP]; f1 = wh[k - INP + 1];
    }
    ushort2 hi, lo;
    hi.x = f2bf(f0); lo.x = f2bf(f0 - bf2f(hi.x));
    hi.y = f2bf(f1); lo.y = f2bf(f1 - bf2f(hi.y));
    unsigned short* base = wfrag + ((size_t)(s * NK16 + k16) * 2) * 512 + lane * 8 + e0;
    *(ushort2*)(base)       = hi;
    *(ushort2*)(base + 512) = lo;
}

// Prep 2: x -> xfrag. Grid (32, 256) = (k16x, t), 256 threads.
__global__ void prep_x(const float* __restrict__ x, unsigned short* __restrict__ xfrag)
{
    const int k16x = blockIdx.x;       // 0..31
    const int t    = blockIdx.y;       // 0..255
    const int tid  = threadIdx.x;
    const int cg   = tid >> 6;         // 0..3
    const int lane = tid & 63;
    const int col  = cg * 32 + (lane & 31);
    const int k0   = k16x * 16 + (lane >> 5) * 8;
    const float* src = x + ((size_t)col * TSTEPS + t) * INP + k0;
    const float4 v0 = *(const float4*)(src);
    const float4 v1 = *(const float4*)(src + 4);
    ushort4 h0, l0, h1, l1;
    h0.x = f2bf(v0.x); l0.x = f2bf(v0.x - bf2f(h0.x));
    h0.y = f2bf(v0.y); l0.y = f2bf(v0.y - bf2f(h0.y));
    h0.z = f2bf(v0.z); l0.z = f2bf(v0.z - bf2f(h0.z));
    h0.w = f2bf(v0.w); l0.w = f2bf(v0.w - bf2f(h0.w));
    h1.x = f2bf(v1.x); l1.x = f2bf(v1.x - bf2f(h1.x));
    h1.y = f2bf(v1.y); l1.y = f2bf(v1.y - bf2f(h1.y));
    h1.z = f2bf(v1.z); l1.z = f2bf(v1.z - bf2f(h1.z));
    h1.w = f2bf(v1.w); l1.w = f2bf(v1.w - bf2f(h1.w));
    unsigned short* base = xfrag +
        ((size_t)(((size_t)t * 32 + k16x) * 4 + cg) * 2) * 512 + lane * 8;
    *(ushort4*)(base)           = h0;
    *(ushort4*)(base + 4)       = h1;
    *(ushort4*)(base + 512)     = l0;
    *(ushort4*)(base + 512 + 4) = l1;
}

// Prep 3: c copy; h0 (H,B) -> hbuf slot 15 (initial h). 512 blocks x 256.
__global__ void prep_state(const float* __restrict__ cin, const float* __restrict__ hin,
                           float* __restrict__ cdst, unsigned short* __restrict__ hslot)
{
    const int idx = blockIdx.x * 256 + threadIdx.x;   // 0..131071
    cdst[idx] = cin[idx];
    const int j = idx >> 7;
    const int b = idx & 127;
    float f = hin[idx];
    unsigned short hh = f2bf(f);
    unsigned short hl = f2bf(f - bf2f(hh));
    const int k16h = j >> 4;
    const int hlf  = (j >> 3) & 1;
    const int e    = j & 7;
    const int cg   = b >> 5;
    const int lane = 32 * hlf + (b & 31);
    unsigned short* base = hslot +
        ((size_t)((k16h * 4 + cg) * 2) * 512) + lane * 8 + e;
    base[0]   = hh;
    base[512] = hl;
}

// ---------------------------------------------------------------------------
// z0 chunk GEMM: z0[t][.] = Wx . x_t + b for t in [tbase, tbase+16).
// Grid (s:128, tq:16) x 512 thr. Block (0,0) also zeroes the barrier words
// for the lstm_chunk that follows (kernel boundary orders the zeroing).
// ---------------------------------------------------------------------------
__global__ __launch_bounds__(512, 2) void gemm_z0(
    const unsigned short* __restrict__ wfrag,
    const unsigned short* __restrict__ xfrag,
    float* __restrict__ z0,
    const float* __restrict__ bg, const float* __restrict__ bi,
    const float* __restrict__ bf_, const float* __restrict__ bo,
    unsigned* __restrict__ bar,
    int tbase)
{
    const int tid  = threadIdx.x;
    if (blockIdx.x == 0 && blockIdx.y == 0) {
        // zero barrier region (512 u32) straight to MALL (agent scope)
        __hip_atomic_store(&bar[tid], 0u, __ATOMIC_RELAXED, __HIP_MEMORY_SCOPE_AGENT);
    }
    const int wv   = tid >> 6;
    const int lane = tid & 63;
    const int l31  = lane & 31;
    const int hl   = lane >> 5;
    const int cw   = wv & 1;
    const int kq   = wv >> 1;              // 0..3
    const int s    = blockIdx.x;           // 0..127
    const int t    = tbase + blockIdx.y;   // timestep
    const int tslot = t & (ZSLOTS - 1);

    const unsigned short* pA = wfrag + ((size_t)(s * NK16 + kq) * 2) * 512 + lane * 8;
    const unsigned short* pB = xfrag + (size_t)t * 131072
                             + (size_t)(4 * kq + 2 * cw) * 1024 + lane * 8;

    f32x16 a0A, a0B, a1A, a1B;
#pragma unroll
    for (int r = 0; r < 16; ++r) { a0A[r]=0.f; a0B[r]=0.f; a1A[r]=0.f; a1B[r]=0.f; }

#pragma unroll
    for (int m = 0; m < 8; ++m) {
        short8 Ah  = LD8(pA);
        short8 Al  = LD8(pA + 512);
        short8 B0h = LD8(pB);
        short8 B0l = LD8(pB + 512);
        short8 B1h = LD8(pB + 1024);
        short8 B1l = LD8(pB + 1536);
        pA += 4096; pB += 16384;
        a0A = MFMA32(Ah, B0h, a0A);
        a1A = MFMA32(Ah, B1h, a1A);
        a0B = MFMA32(Ah, B0l, a0B);
        a1B = MFMA32(Ah, B1l, a1B);
        a0A = MFMA32(Al, B0h, a0A);
        a1A = MFMA32(Al, B1h, a1A);
    }

    __shared__ float part[2][32][128];     // 32 KB

    if (kq >= 2) {
#pragma unroll
        for (int r = 0; r < 16; ++r) {
            const int lr = (r & 3) + 8 * (r >> 2) + 4 * hl;
            part[kq - 2][lr][(2 * cw)     * 32 + l31] = a0A[r] + a0B[r];
            part[kq - 2][lr][(2 * cw + 1) * 32 + l31] = a1A[r] + a1B[r];
        }
    }
    __syncthreads();
    if (kq < 2) {
#pragma unroll
        for (int r = 0; r < 16; ++r) {
            const int lr = (r & 3) + 8 * (r >> 2) + 4 * hl;
            part[kq][lr][(2 * cw)     * 32 + l31] += a0A[r] + a0B[r];
            part[kq][lr][(2 * cw + 1) * 32 + l31] += a1A[r] + a1B[r];
        }
    }
    __syncthreads();

    {
        const int lr = tid >> 4;
        const int c0 = (tid & 15) * 8;
        const int g  = lr & 3;
        const int j  = s * 8 + (lr >> 2);
        const float bb = (g == 0 ? bg : g == 1 ? bi : g == 2 ? bf_ : bo)[j];
        float z[8];
#pragma unroll
        for (int cc = 0; cc < 8; ++cc)
            z[cc] = part[0][lr][c0 + cc] + part[1][lr][c0 + cc] + bb;
        float* dst = z0 + (((size_t)tslot * 128 + s) * 32 + lr) * 128 + c0;
        *(float4*)(dst)     = make_float4(z[0], z[1], z[2], z[3]);
        *(float4*)(dst + 4) = make_float4(z[4], z[5], z[6], z[7]);
    }
}

// ---------------------------------------------------------------------------
// Fence-free 2-level grid barrier. NO cache maintenance ops (no wbl2/inv):
// all data transport is via sc1 stores (h) or fresh-address cached reads.
//   bar[grp*32 + tt] : per-group arrival counter for step tt (used once)
//   bar[256 + tt]    : root counter for step tt
//   bar[288]         : generation word (monotonic 1..15 within a chunk)
// All words pre-zeroed by the preceding gemm_z0 dispatch.
// ---------------------------------------------------------------------------
static __device__ __forceinline__ void grid_barrier2(unsigned* __restrict__ bar,
                                                     int tt, int bx)
{
    // drain our wave's outstanding stores (h sc1 stores -> at MALL once retired)
    asm volatile("s_waitcnt vmcnt(0)" ::: "memory");
    __syncthreads();
    if (threadIdx.x == 0) {
        const int grp = bx & 7;
        unsigned a = __hip_atomic_fetch_add(&bar[grp * 32 + tt], 1u,
                                            __ATOMIC_RELAXED, __HIP_MEMORY_SCOPE_AGENT);
        if (a == (unsigned)(NBLK_CHUNK / 8 - 1)) {
            unsigned r = __hip_atomic_fetch_add(&bar[256 + tt], 1u,
                                                __ATOMIC_RELAXED, __HIP_MEMORY_SCOPE_AGENT);
            if (r == 7u)
                __hip_atomic_store(&bar[288], (unsigned)(tt + 1),
                                   __ATOMIC_RELAXED, __HIP_MEMORY_SCOPE_AGENT);
        }
        while (__hip_atomic_load(&bar[288], __ATOMIC_RELAXED,
                                 __HIP_MEMORY_SCOPE_AGENT) < (unsigned)(tt + 1))
            __builtin_amdgcn_s_sleep(4);
    }
    __syncthreads();
}

// ---------------------------------------------------------------------------
// Persistent chunk: 16 LSTM timesteps in ONE launch. W h-slice in registers
// (loaded once; L2 stays warm anyway since there are no invalidates), c in a
// register, h exchanged through rotating MALL-coherent slots. Grid 256 x 512,
// LDS 66 KB -> 1+ block/CU, all 256 blocks co-resident (no deadlock).
// ---------------------------------------------------------------------------
__global__ __launch_bounds__(512, 1) void lstm_chunk(
    const unsigned short* __restrict__ wfrag,
    const float* __restrict__ z0,
    unsigned short* __restrict__ hbuf,
    float* __restrict__ cst,
    float* __restrict__ outf,
    unsigned* __restrict__ bar,
    int tbase)
{
    const int tid  = threadIdx.x;
    const int wv   = tid >> 6;             // K-slice 0..7
    const int lane = tid & 63;
    const int l31  = lane & 31;
    const int hl   = lane >> 5;
    const int bx   = blockIdx.x;

    const int xcd     = bx & 7;
    const int ii      = bx >> 3;
    const int s       = xcd * 16 + (ii >> 1);   // rowslice 0..127
    const int cb      = ii & 1;                 // col half
    const int colbase = cb << 6;
    const int J0      = s * 8;

    // epilogue role: thread = (jloc = tid>>6, cl = tid&63)
    const int ejl  = tid >> 6;
    const int ecl  = tid & 63;
    const int ej   = J0 + ejl;
    const int ecol = colbase + ecl;
    const size_t ci = (size_t)ej * BATCH + ecol;

    // W h-part -> registers (16 x short8), once per chunk.
    short8 WAh[8], WAl[8];
    {
        const unsigned short* pA = wfrag +
            ((size_t)(s * NK16 + 32 + wv) * 2) * 512 + lane * 8;
#pragma unroll
        for (int m = 0; m < 8; ++m) {
            WAh[m] = LD8(pA);
            WAl[m] = LD8(pA + 512);
            pA += 8192;
        }
    }
    float creg = cst[ci];                    // c lives in a register all chunk
    const size_t bOff = (size_t)(4 * wv + 2 * cb) * 1024 + lane * 8;

    const int k16h = s >> 1;                 // h-scatter constants

    __shared__ float part[8][32][64];                  // 64 KB
    __shared__ unsigned long long hstage[256];         // 2 KB coalescing stage
    unsigned short* hs16 = (unsigned short*)hstage;

    // z0 preload for first step of the chunk
    float nadd0, nadd1, nadd2, nadd3;
    {
        const float* zp = z0 + (((size_t)(tbase & (ZSLOTS - 1)) * 128 + s) * 32
                                + 4 * ejl) * 128 + ecol;
        nadd0 = zp[0]; nadd1 = zp[128]; nadd2 = zp[256]; nadd3 = zp[384];
    }

#pragma unroll 1
    for (int tt = 0; tt < ZSLOTS; ++tt) {
        const int t = tbase + tt;
        const unsigned short* hin  = hbuf + (size_t)((tt + ZSLOTS - 1) & (ZSLOTS - 1)) * HSLOT;
        unsigned short*       hout = hbuf + (size_t)tt * HSLOT;
        const float add0 = nadd0, add1 = nadd1, add2 = nadd2, add3 = nadd3;

        f32x16 a0A, a0B, a1A, a1B;
#pragma unroll
        for (int r = 0; r < 16; ++r) { a0A[r]=0.f; a0B[r]=0.f; a1A[r]=0.f; a1B[r]=0.f; }

        // h-only K-loop: k16h = 8m + wv, W from registers. Plain cached loads:
        // slot lines are cold in this L2 (first touch this kernel) -> fetch
        // the fresh MALL data written by last step's sc1 stores.
        const unsigned short* pH = hin + bOff;
#pragma unroll
        for (int m = 0; m < 8; ++m) {
            short8 B0h = LD8(pH);
            short8 B0l = LD8(pH + 512);
            short8 B1h = LD8(pH + 1024);
            short8 B1l = LD8(pH + 1536);
            pH += 32768;
            a0A = MFMA32(WAh[m], B0h, a0A);
            a1A = MFMA32(WAh[m], B1h, a1A);
            a0B = MFMA32(WAh[m], B0l, a0B);
            a1B = MFMA32(WAh[m], B1l, a1B);
            a0A = MFMA32(WAl[m], B0h, a0A);
            a1A = MFMA32(WAl[m], B1h, a1A);
        }

        // single-stage K-partial dump: all 8 waves, one barrier.
#pragma unroll
        for (int r = 0; r < 16; ++r) {
            const int lr = (r & 3) + 8 * (r >> 2) + 4 * hl;
            part[wv][lr][l31]      = a0A[r] + a0B[r];
            part[wv][lr][32 + l31] = a1A[r] + a1B[r];
        }
        __syncthreads();

        // gates: thread (ejl, ecl); sum 8 K-partials per gate; stage h in LDS.
        {
            const int r0 = 4 * ejl;
            float z0g = add0, z1g = add1, z2g = add2, z3g = add3;
#pragma unroll
            for (int p = 0; p < 8; ++p) {
                z0g += part[p][r0 + 0][ecl];
                z1g += part[p][r0 + 1][ecl];
                z2g += part[p][r0 + 2][ecl];
                z3g += part[p][r0 + 3][ecl];
            }
            float gg = tanh_f(z0g);
            float ig = sigmoid_f(z1g);
            float fg = sigmoid_f(z2g);
            float og = sigmoid_f(z3g);
            float cn = gg * ig + creg * fg;
            creg = cn;
            float hh = tanh_f(cn) * og;
            unsigned short hb  = f2bf(hh);
            unsigned short hlo = f2bf(hh - bf2f(hb));
            // LDS stage in output-region order: region r = (ecl>>5)*2 + p,
            // within-region ushort idx = (ecl&31)*8 + ejl.
            hs16[((ecl >> 5) * 2 + 0) * 256 + (ecl & 31) * 8 + ejl] = hb;
            hs16[((ecl >> 5) * 2 + 1) * 256 + (ecl & 31) * 8 + ejl] = hlo;
            if (outf && t == TSTEPS - 1) outf[ci] = hh;
        }
        __syncthreads();

        // coalesced h store: 256 threads x u64, agent-scope (sc1 -> MALL).
        // Block output = 4 contiguous 512B regions of hout:
        //   region r: cg = 2*cb + (r>>1), p = r&1,
        //   ushort off = ((k16h*4+cg)*2+p)*512 + 32*(s&1)*8 + (tid&63)*4
        if (tid < 256) {
            const int r   = tid >> 6;
            const int w   = tid & 63;
            const int cgg = 2 * cb + (r >> 1);
            const int p   = r & 1;
            const size_t uo = ((size_t)((k16h * 4 + cgg) * 2 + p)) * 512
                            + 32 * (s & 1) * 8 + w * 4;
            __hip_atomic_store((unsigned long long*)(hout + uo), hstage[tid],
                               __ATOMIC_RELAXED, __HIP_MEMORY_SCOPE_AGENT);
        }

        if (tt + 1 < ZSLOTS) {
            // drain h stores, then issue next-step z0 prefetch so its latency
            // hides under the barrier spin.
            asm volatile("s_waitcnt vmcnt(0)" ::: "memory");
            __syncthreads();
            const float* zn = z0 + (((size_t)((t + 1) & (ZSLOTS - 1)) * 128 + s) * 32
                                    + 4 * ejl) * 128 + ecol;
            nadd0 = zn[0]; nadd1 = zn[128]; nadd2 = zn[256]; nadd3 = zn[384];
            if (tid == 0) {
                const int grp = bx & 7;
                unsigned a = __hip_atomic_fetch_add(&bar[grp * 32 + tt], 1u,
                                __ATOMIC_RELAXED, __HIP_MEMORY_SCOPE_AGENT);
                if (a == (unsigned)(NBLK_CHUNK / 8 - 1)) {
                    unsigned rr = __hip_atomic_fetch_add(&bar[256 + tt], 1u,
                                    __ATOMIC_RELAXED, __HIP_MEMORY_SCOPE_AGENT);
                    if (rr == 7u)
                        __hip_atomic_store(&bar[288], (unsigned)(tt + 1),
                                           __ATOMIC_RELAXED, __HIP_MEMORY_SCOPE_AGENT);
                }
                while (__hip_atomic_load(&bar[288], __ATOMIC_RELAXED,
                                         __HIP_MEMORY_SCOPE_AGENT) < (unsigned)(tt + 1))
                    __builtin_amdgcn_s_sleep(4);
            }
            __syncthreads();
        }
    }
    cst[ci] = creg;
}

// ---------------------------------------------------------------------------
// Fallback per-step kernel (used only if ws too small for mode A).
// ---------------------------------------------------------------------------
__global__ __launch_bounds__(512, 1) void lstm_step(
    const unsigned short* __restrict__ wfrag,
    const unsigned short* __restrict__ xfrag,
    const unsigned short* __restrict__ hin,
    unsigned short* __restrict__ hout,
    float* __restrict__ cst,
    const float* __restrict__ bg, const float* __restrict__ bi,
    const float* __restrict__ bf_, const float* __restrict__ bo,
    float* __restrict__ outf, int t)
{
    const int tid  = threadIdx.x;
    const int wv   = tid >> 6;
    const int lane = tid & 63;
    const int l31  = lane & 31;
    const int hl   = lane >> 5;
    const int bx   = blockIdx.x;

    const int xcd     = bx & 7;
    const int ii      = bx >> 3;
    const int s       = xcd * 16 + (ii >> 1);
    const int cb      = ii & 1;
    const int colbase = cb << 6;
    const int J0      = s * 8;

    const int ejl  = tid >> 6;
    const int ecl  = tid & 63;
    const int ej   = J0 + ejl;
    const int ecol = colbase + ecl;

    float add0 = bg[ej], add1 = bi[ej], add2 = bf_[ej], add3 = bo[ej];
    const size_t ci = (size_t)ej * BATCH + ecol;
    float cold = cst[ci];

    f32x16 a0A, a0B, a1A, a1B;
#pragma unroll
    for (int r = 0; r < 16; ++r) { a0A[r]=0.f; a0B[r]=0.f; a1A[r]=0.f; a1B[r]=0.f; }

    const size_t bOff = (size_t)(4 * wv + 2 * cb) * 1024 + lane * 8;

    {
        const unsigned short* pA = wfrag + ((size_t)(s * NK16 + wv) * 2) * 512 + lane * 8;
        const unsigned short* pX = xfrag + (size_t)t * 131072 + bOff;
#pragma unroll
        for (int m = 0; m < 4; ++m) {
            short8 Ah  = LD8(pA);
            short8 Al  = LD8(pA + 512);
            short8 B0h = LD8(pX);
            short8 B0l = LD8(pX + 512);
            short8 B1h = LD8(pX + 1024);
            short8 B1l = LD8(pX + 1536);
            pA += 8192; pX += 32768;
            a0A = MFMA32(Ah, B0h, a0A);
            a1A = MFMA32(Ah, B1h, a1A);
            a0B = MFMA32(Ah, B0l, a0B);
            a1B = MFMA32(Ah, B1l, a1B);
            a0A = MFMA32(Al, B0h, a0A);
            a1A = MFMA32(Al, B1h, a1A);
        }
        const unsigned short* pH = hin + bOff;
#pragma unroll
        for (int m = 0; m < 8; ++m) {
            short8 Ah  = LD8(pA);
            short8 Al  = LD8(pA + 512);
            short8 B0h = LD8(pH);
            short8 B0l = LD8(pH + 512);
            short8 B1h = LD8(pH + 1024);
            short8 B1l = LD8(pH + 1536);
            pA += 8192; pH += 32768;
            a0A = MFMA32(Ah, B0h, a0A);
            a1A = MFMA32(Ah, B1h, a1A);
            a0B = MFMA32(Ah, B0l, a0B);
            a1B = MFMA32(Ah, B1l, a1B);
            a0A = MFMA32(Al, B0h, a0A);
            a1A = MFMA32(Al, B1h, a1A);
        }
    }

    __shared__ float part[8][32][64];
#pragma unroll
    for (int r = 0; r < 16; ++r) {
        const int lr = (r & 3) + 8 * (r >> 2) + 4 * hl;
        part[wv][lr][l31]      = a0A[r] + a0B[r];
        part[wv][lr][32 + l31] = a1A[r] + a1B[r];
    }
    __syncthreads();

    {
        const int r0 = 4 * ejl;
        float z0g = add0, z1g = add1, z2g = add2, z3g = add3;
#pragma unroll
        for (int p = 0; p < 8; ++p) {
            z0g += part[p][r0 + 0][ecl];
            z1g += part[p][r0 + 1][ecl];
            z2g += part[p][r0 + 2][ecl];
            z3g += part[p][r0 + 3][ecl];
        }
        float gg = tanh_f(z0g);
        float ig = sigmoid_f(z1g);
        float fg = sigmoid_f(z2g);
        float og = sigmoid_f(z3g);
        float cn = gg * ig + cold * fg;
        cst[ci] = cn;
        float hh = tanh_f(cn) * og;
        unsigned short hb  = f2bf(hh);
        unsigned short hlo = f2bf(hh - bf2f(hb));
        const int k16h  = s >> 1;
        const int cgg   = (colbase >> 5) + (ecl >> 5);
        const int lane8 = 32 * (s & 1) + (ecl & 31);
        unsigned short* dst = hout +
            ((size_t)((k16h * 4 + cgg) * 2) * 512) + lane8 * 8 + ejl;
        dst[0]   = hb;
        dst[512] = hlo;
        if (outf) outf[ci] = hh;
    }
}

// ---------------------------------------------------------------------------
extern "C" void kernel_launch(void* const* d_in, const int* in_sizes, int n_in,
                              void* d_out, int out_size, void* d_ws, size_t ws_size,
                              hipStream_t stream)
{
    const float* x   = (const float*)d_in[0];
    const float* c0v = (const float*)d_in[1];
    const float* h0v = (const float*)d_in[2];
    const float* Wgx = (const float*)d_in[3];
    const float* Wix = (const float*)d_in[4];
    const float* Wfx = (const float*)d_in[5];
    const float* Wox = (const float*)d_in[6];
    const float* Wgh = (const float*)d_in[7];
    const float* Wih = (const float*)d_in[8];
    const float* Wfh = (const float*)d_in[9];
    const float* Woh = (const float*)d_in[10];
    const float* bg  = (const float*)d_in[11];
    const float* bi  = (const float*)d_in[12];
    const float* bf  = (const float*)d_in[13];
    const float* bo  = (const float*)d_in[14];

    // ws layout (ushort unless noted):
    //   wfrag 25.2 MB | xfrag 67.1 MB | hbuf 16 x 0.5 MB = 8.4 MB
    //   cst 0.5 MB (f32) | z0 33.6 MB (f32) | bar 2 KB  => ~135 MB
    unsigned short* wfrag = (unsigned short*)d_ws;
    unsigned short* xfrag = wfrag + (size_t)128 * NK16 * 2 * 512;
    unsigned short* hbuf  = xfrag + (size_t)TSTEPS * 32 * 4 * 2 * 512;
    float* cst            = (float*)(hbuf + (size_t)ZSLOTS * HSLOT);
    float* z0             = (float*)(cst + (size_t)HID * BATCH);
    unsigned* bar         = (unsigned*)(z0 + (size_t)ZSLOTS * 4096 * 128);

    const size_t needA = (size_t)((char*)(bar + 512) - (char*)d_ws);
    const bool useA = (ws_size >= needA);

    float* outp = (float*)d_out;

    prep_w<<<dim3(NK16, 128), dim3(256), 0, stream>>>(Wgx, Wix, Wfx, Wox,
                                                      Wgh, Wih, Wfh, Woh, wfrag);
    prep_x<<<dim3(32, TSTEPS), dim3(256), 0, stream>>>(x, xfrag);
    prep_state<<<dim3(512), dim3(256), 0, stream>>>(c0v, h0v, cst,
                                                    hbuf + (size_t)(ZSLOTS - 1) * HSLOT);

    if (useA) {
        for (int q = 0; q < TSTEPS / ZSLOTS; ++q) {
            gemm_z0<<<dim3(128, ZSLOTS), dim3(512), 0, stream>>>(
                wfrag, xfrag, z0, bg, bi, bf, bo, bar, q * ZSLOTS);
            lstm_chunk<<<dim3(NBLK_CHUNK), dim3(512), 0, stream>>>(
                wfrag, z0, hbuf, cst, outp, bar, q * ZSLOTS);
        }
    } else {
        // mode-B: per-step dispatches, h via slots 15/14, bias-only adds,
        // full K (x + h) every step.
        unsigned short* hfA = hbuf + (size_t)(ZSLOTS - 1) * HSLOT;  // initial h
        unsigned short* hfB = hbuf + (size_t)(ZSLOTS - 2) * HSLOT;
        for (int t = 0; t < TSTEPS; ++t) {
            const unsigned short* hin = (t & 1) ? hfB : hfA;
            unsigned short* hout      = (t & 1) ? hfA : hfB;
            lstm_step<<<dim3(256), dim3(512), 0, stream>>>(
                wfrag, xfrag, hin, hout,
                cst, bg, bi, bf, bo,
                (t == TSTEPS - 1) ? outp : nullptr, t);
        }
    }
}

// Round 4
// 2296.689 us; speedup vs baseline: 4.8985x; 1.7467x over previous
//
#include <hip/hip_runtime.h>
#include <cstdint>
#include <cstddef>

#define HID 1024
#define INP 512
#define BATCH 128
#define TSTEPS 256
#define NK16 96         // K/16 total (x: 0..31, h: 32..95)
#define HSLOTS 32       // h slot rotation depth (t mod 32)
#define NBLK_CHUNK 256  // persistent grid size (co-residency enforced by coop launch)
#define HSLOT ((size_t)64 * 4 * 2 * 512)   // ushorts per h slot (0.5 MB)

using short8  = __attribute__((ext_vector_type(8))) short;
using f32x16  = __attribute__((ext_vector_type(16))) float;

#define LD8(p) (*(const short8*)(p))
#define MFMA32(a,b,c) __builtin_amdgcn_mfma_f32_32x32x16_bf16((a),(b),(c),0,0,0)

static __device__ __forceinline__ unsigned short f2bf(float f) {
    union { float f; unsigned int u; } v; v.f = f;
    unsigned int r = v.u + 0x7fffu + ((v.u >> 16) & 1u);   // RNE
    return (unsigned short)(r >> 16);
}
static __device__ __forceinline__ float bf2f(unsigned short b) {
    union { unsigned int u; float f; } v; v.u = ((unsigned int)b) << 16;
    return v.f;
}
static __device__ __forceinline__ float sigmoid_f(float z) {
    return 1.0f / (1.0f + __expf(-z));
}
static __device__ __forceinline__ float tanh_f(float z) {
    return 2.0f / (1.0f + __expf(-2.0f * z)) - 1.0f;
}

// ---------------------------------------------------------------------------
// Fragment layouts (32x32x16 MFMA; verified):
//   A: lane l holds W[s*32 + (l&31)][k16*16 + (l>>5)*8 + e]
//      wfrag[s:128][k16:96][p:2][lane:64][e:8]   (p: 0=hi, 1=lo)
//   B: lane l holds act[col = cg*32 + (l&31)][k16*16 + (l>>5)*8 + e]
//      xfrag[t:256][k16:32][cg:4][p:2][lane:64][e:8]
//      hbuf[slot:32][k16:64][cg:4][p:2][lane:64][e:8]   (rotating slots)
//
// Cross-block h transport (fence-free in steady state): producers write h
// into slot (t&31) with agent-scope relaxed atomic u64 stores (sc1 ->
// write-through to MALL). Readers use plain cached loads: slot addresses
// are fresh for 32 consecutive steps, so reads are cold L2 misses hitting
// current MALL data. Every 32 steps all blocks issue ONE acquire fence
// (L1/L2 invalidate) between the sweep and the h reads, which covers every
// slot-address reuse. Block skew is bounded by 1 step by the flag sweep.
//
// Grid barrier (RMW-free): block b's tid0 stores flags[b] = t+1 (monotonic)
// after its h stores drain; every block then sweeps all 256 flags in
// parallel (tid<256, one load each + __syncthreads_count) until all >= t.
// No atomic contention, no publish hop, no counter reset.
// Hang-safety: launched cooperatively (runtime guarantees co-residency or
// returns an error -> host falls back to per-step dispatches); the sweep
// additionally has a generous iteration bound so it can never spin forever.
// ---------------------------------------------------------------------------

// Prep 1: weights -> wfrag. Grid (96, 128) = (k16, s), 256 threads.
__global__ void prep_w(const float* __restrict__ Wgx, const float* __restrict__ Wix,
                       const float* __restrict__ Wfx, const float* __restrict__ Wox,
                       const float* __restrict__ Wgh, const float* __restrict__ Wih,
                       const float* __restrict__ Wfh, const float* __restrict__ Woh,
                       unsigned short* __restrict__ wfrag)
{
    const int k16 = blockIdx.x;        // 0..95
    const int s   = blockIdx.y;        // 0..127
    const int tid  = threadIdx.x;
    const int lane = tid >> 2;         // 0..63
    const int e0   = (tid & 3) * 2;    // 0,2,4,6
    const int row  = s * 32 + (lane & 31);
    const int k    = k16 * 16 + (lane >> 5) * 8 + e0;
    const int j = row >> 2;
    const int g = row & 3;
    float f0, f1;
    if (k < INP) {
        const float* wx = (g == 0 ? Wgx : g == 1 ? Wix : g == 2 ? Wfx : Wox) + (size_t)j * INP;
        f0 = wx[k]; f1 = wx[k + 1];
    } else {
        const float* wh = (g == 0 ? Wgh : g == 1 ? Wih : g == 2 ? Wfh : Woh) + (size_t)j * HID;
        f0 = wh[k - INP]; f1 = wh[k - INP + 1];
    }
    ushort2 hi, lo;
    hi.x = f2bf(f0); lo.x = f2bf(f0 - bf2f(hi.x));
    hi.y = f2bf(f1); lo.y = f2bf(f1 - bf2f(hi.y));
    unsigned short* base = wfrag + ((size_t)(s * NK16 + k16) * 2) * 512 + lane * 8 + e0;
    *(ushort2*)(base)       = hi;
    *(ushort2*)(base + 512) = lo;
}

// Prep 2: x -> xfrag. Grid (32, 256) = (k16x, t), 256 threads.
__global__ void prep_x(const float* __restrict__ x, unsigned short* __restrict__ xfrag)
{
    const int k16x = blockIdx.x;       // 0..31
    const int t    = blockIdx.y;       // 0..255
    const int tid  = threadIdx.x;
    const int cg   = tid >> 6;         // 0..3
    const int lane = tid & 63;
    const int col  = cg * 32 + (lane & 31);
    const int k0   = k16x * 16 + (lane >> 5) * 8;
    const float* src = x + ((size_t)col * TSTEPS + t) * INP + k0;
    const float4 v0 = *(const float4*)(src);
    const float4 v1 = *(const float4*)(src + 4);
    ushort4 h0, l0, h1, l1;
    h0.x = f2bf(v0.x); l0.x = f2bf(v0.x - bf2f(h0.x));
    h0.y = f2bf(v0.y); l0.y = f2bf(v0.y - bf2f(h0.y));
    h0.z = f2bf(v0.z); l0.z = f2bf(v0.z - bf2f(h0.z));
    h0.w = f2bf(v0.w); l0.w = f2bf(v0.w - bf2f(h0.w));
    h1.x = f2bf(v1.x); l1.x = f2bf(v1.x - bf2f(h1.x));
    h1.y = f2bf(v1.y); l1.y = f2bf(v1.y - bf2f(h1.y));
    h1.z = f2bf(v1.z); l1.z = f2bf(v1.z - bf2f(h1.z));
    h1.w = f2bf(v1.w); l1.w = f2bf(v1.w - bf2f(h1.w));
    unsigned short* base = xfrag +
        ((size_t)(((size_t)t * 32 + k16x) * 4 + cg) * 2) * 512 + lane * 8;
    *(ushort4*)(base)           = h0;
    *(ushort4*)(base + 4)       = h1;
    *(ushort4*)(base + 512)     = l0;
    *(ushort4*)(base + 512 + 4) = l1;
}

// Prep 3: c copy; h0 (H,B) -> hbuf slot 31 (initial h); zero flags.
__global__ void prep_state(const float* __restrict__ cin, const float* __restrict__ hin,
                           float* __restrict__ cdst, unsigned short* __restrict__ hslot,
                           unsigned* __restrict__ flags)
{
    if (blockIdx.x == 0) flags[threadIdx.x] = 0u;   // 256 flags (256 thr/blk)
    const int idx = blockIdx.x * 256 + threadIdx.x;   // 0..131071
    cdst[idx] = cin[idx];
    const int j = idx >> 7;
    const int b = idx & 127;
    float f = hin[idx];
    unsigned short hh = f2bf(f);
    unsigned short hl = f2bf(f - bf2f(hh));
    const int k16h = j >> 4;
    const int hlf  = (j >> 3) & 1;
    const int e    = j & 7;
    const int cg   = b >> 5;
    const int lane = 32 * hlf + (b & 31);
    unsigned short* base = hslot +
        ((size_t)((k16h * 4 + cg) * 2) * 512) + lane * 8 + e;
    base[0]   = hh;
    base[512] = hl;
}

// ---------------------------------------------------------------------------
// Persistent kernel: ALL 256 LSTM timesteps in ONE (cooperative) launch.
// Per step: (1) x-part MFMA (independent of h -> hidden under stragglers),
// (2) flag sweep, (3) [every 32 steps] acquire fence, (4) h-part MFMA,
// (5) LDS K-reduce + gates, (6) coalesced sc1 h store + drain + flag.
// ---------------------------------------------------------------------------
__global__ __launch_bounds__(512, 1) void lstm_persist(
    const unsigned short* __restrict__ wfrag,
    const unsigned short* __restrict__ xfrag,
    unsigned short* __restrict__ hbuf,
    float* __restrict__ cst,
    const float* __restrict__ bg, const float* __restrict__ bi,
    const float* __restrict__ bf_, const float* __restrict__ bo,
    float* __restrict__ outf,
    unsigned* __restrict__ flags)
{
    const int tid  = threadIdx.x;
    const int wv   = tid >> 6;             // K-slice 0..7
    const int lane = tid & 63;
    const int l31  = lane & 31;
    const int hl   = lane >> 5;
    const int bx   = blockIdx.x;

    const int xcd     = bx & 7;
    const int ii      = bx >> 3;
    const int s       = xcd * 16 + (ii >> 1);   // rowslice 0..127
    const int cb      = ii & 1;                 // col half
    const int colbase = cb << 6;

    // epilogue role: thread = (jloc = tid>>6, cl = tid&63)
    const int ejl  = tid >> 6;
    const int ecl  = tid & 63;
    const int ej   = s * 8 + ejl;
    const int ecol = colbase + ecl;
    const size_t ci = (size_t)ej * BATCH + ecol;

    const float bias0 = bg[ej], bias1 = bi[ej], bias2 = bf_[ej], bias3 = bo[ej];
    float creg = cst[ci];                    // c lives in a register all 256 steps

    const size_t bOff = (size_t)(4 * wv + 2 * cb) * 1024 + lane * 8;
    const int k16h = s >> 1;                 // h-scatter constant

    const unsigned short* pAx0 = wfrag + ((size_t)(s * NK16 + wv) * 2) * 512 + lane * 8;
    const unsigned short* pAh0 = wfrag + ((size_t)(s * NK16 + 32 + wv) * 2) * 512 + lane * 8;

    __shared__ float part[8][32][64];                  // 64 KB
    __shared__ unsigned long long hstage[256];         // 2 KB coalescing stage
    unsigned short* hs16 = (unsigned short*)hstage;

#pragma unroll 1
    for (int t = 0; t < TSTEPS; ++t) {
        f32x16 a0A, a0B, a1A, a1B;
#pragma unroll
        for (int r = 0; r < 16; ++r) { a0A[r]=0.f; a0B[r]=0.f; a1A[r]=0.f; a1B[r]=0.f; }

        // ---- x-part (independent of h; overlaps other blocks' step t-1 tail)
        {
            const unsigned short* pA = pAx0;
            const unsigned short* pX = xfrag + (size_t)t * 131072 + bOff;
#pragma unroll
            for (int m = 0; m < 4; ++m) {
                short8 Ah  = LD8(pA);
                short8 Al  = LD8(pA + 512);
                short8 B0h = LD8(pX);
                short8 B0l = LD8(pX + 512);
                short8 B1h = LD8(pX + 1024);
                short8 B1l = LD8(pX + 1536);
                pA += 8192; pX += 32768;
                a0A = MFMA32(Ah, B0h, a0A);
                a1A = MFMA32(Ah, B1h, a1A);
                a0B = MFMA32(Ah, B0l, a0B);
                a1B = MFMA32(Ah, B1l, a1B);
                a0A = MFMA32(Al, B0h, a0A);
                a1A = MFMA32(Al, B1h, a1A);
            }
        }

        // ---- flag sweep: wait until all 256 blocks finished step t-1.
        if (t > 0) {
            const unsigned target = (unsigned)t;
            int done;
            int guard = 0;
            do {
                unsigned v = target;
                if (tid < 256)
                    v = __hip_atomic_load(&flags[tid], __ATOMIC_RELAXED,
                                          __HIP_MEMORY_SCOPE_AGENT);
                done = __syncthreads_count(v >= target);
                if (done < 512) __builtin_amdgcn_s_sleep(1);
            } while (done < 512 && ++guard < (1 << 20));   // bounded: never hangs
            asm volatile("" ::: "memory");   // no hoisting h loads above sweep
            __builtin_amdgcn_sched_barrier(0);
            // periodic L1/L2 invalidate covering slot-address reuse (32-step
            // rotation). Placed after sweep (producers done), before h reads.
            if ((t & 31) == 0)
                __builtin_amdgcn_fence(__ATOMIC_ACQUIRE, "agent");
        }

        // ---- h-part: k16h = 8m + wv, plain cached loads of fresh slot.
        {
            const unsigned short* pA = pAh0;
            const unsigned short* pH = hbuf + (size_t)((t + HSLOTS - 1) & (HSLOTS - 1)) * HSLOT + bOff;
#pragma unroll
            for (int m = 0; m < 8; ++m) {
                short8 Ah  = LD8(pA);
                short8 Al  = LD8(pA + 512);
                short8 B0h = LD8(pH);
                short8 B0l = LD8(pH + 512);
                short8 B1h = LD8(pH + 1024);
                short8 B1l = LD8(pH + 1536);
                pA += 8192; pH += 32768;
                a0A = MFMA32(Ah, B0h, a0A);
                a1A = MFMA32(Ah, B1h, a1A);
                a0B = MFMA32(Ah, B0l, a0B);
                a1B = MFMA32(Ah, B1l, a1B);
                a0A = MFMA32(Al, B0h, a0A);
                a1A = MFMA32(Al, B1h, a1A);
            }
        }

        // ---- single-stage K-partial dump: all 8 waves, one barrier.
#pragma unroll
        for (int r = 0; r < 16; ++r) {
            const int lr = (r & 3) + 8 * (r >> 2) + 4 * hl;
            part[wv][lr][l31]      = a0A[r] + a0B[r];
            part[wv][lr][32 + l31] = a1A[r] + a1B[r];
        }
        __syncthreads();

        // ---- gates: thread (ejl, ecl); sum 8 K-partials per gate.
        {
            const int r0 = 4 * ejl;
            float z0g = bias0, z1g = bias1, z2g = bias2, z3g = bias3;
#pragma unroll
            for (int p = 0; p < 8; ++p) {
                z0g += part[p][r0 + 0][ecl];
                z1g += part[p][r0 + 1][ecl];
                z2g += part[p][r0 + 2][ecl];
                z3g += part[p][r0 + 3][ecl];
            }
            float gg = tanh_f(z0g);
            float ig = sigmoid_f(z1g);
            float fg = sigmoid_f(z2g);
            float og = sigmoid_f(z3g);
            float cn = gg * ig + creg * fg;
            creg = cn;
            float hh = tanh_f(cn) * og;
            unsigned short hb  = f2bf(hh);
            unsigned short hlo = f2bf(hh - bf2f(hb));
            hs16[((ecl >> 5) * 2 + 0) * 256 + (ecl & 31) * 8 + ejl] = hb;
            hs16[((ecl >> 5) * 2 + 1) * 256 + (ecl & 31) * 8 + ejl] = hlo;
            if (outf && t == TSTEPS - 1) outf[ci] = hh;
        }
        __syncthreads();

        // ---- coalesced h store: 256 threads x u64, agent-scope (sc1 -> MALL).
        {
            unsigned short* hout = hbuf + (size_t)(t & (HSLOTS - 1)) * HSLOT;
            if (tid < 256) {
                const int r   = tid >> 6;
                const int w   = tid & 63;
                const int cgg = 2 * cb + (r >> 1);
                const int p   = r & 1;
                const size_t uo = ((size_t)((k16h * 4 + cgg) * 2 + p)) * 512
                                + 32 * (s & 1) * 8 + w * 4;
                __hip_atomic_store((unsigned long long*)(hout + uo), hstage[tid],
                                   __ATOMIC_RELAXED, __HIP_MEMORY_SCOPE_AGENT);
            }
        }
        // drain h stores to the coherence point, then raise our flag.
        asm volatile("s_waitcnt vmcnt(0)" ::: "memory");
        __syncthreads();
        if (tid == 0)
            __hip_atomic_store(&flags[bx], (unsigned)(t + 1),
                               __ATOMIC_RELAXED, __HIP_MEMORY_SCOPE_AGENT);
    }
    cst[ci] = creg;
}

// ---------------------------------------------------------------------------
// Fallback per-step kernel (used if coop launch unavailable or ws too small).
// ---------------------------------------------------------------------------
__global__ __launch_bounds__(512, 1) void lstm_step(
    const unsigned short* __restrict__ wfrag,
    const unsigned short* __restrict__ xfrag,
    const unsigned short* __restrict__ hin,
    unsigned short* __restrict__ hout,
    float* __restrict__ cst,
    const float* __restrict__ bg, const float* __restrict__ bi,
    const float* __restrict__ bf_, const float* __restrict__ bo,
    float* __restrict__ outf, int t)
{
    const int tid  = threadIdx.x;
    const int wv   = tid >> 6;
    const int lane = tid & 63;
    const int l31  = lane & 31;
    const int hl   = lane >> 5;
    const int bx   = blockIdx.x;

    const int xcd     = bx & 7;
    const int ii      = bx >> 3;
    const int s       = xcd * 16 + (ii >> 1);
    const int cb      = ii & 1;
    const int colbase = cb << 6;

    const int ejl  = tid >> 6;
    const int ecl  = tid & 63;
    const int ej   = s * 8 + ejl;
    const int ecol = colbase + ecl;

    float add0 = bg[ej], add1 = bi[ej], add2 = bf_[ej], add3 = bo[ej];
    const size_t ci = (size_t)ej * BATCH + ecol;
    float cold = cst[ci];

    f32x16 a0A, a0B, a1A, a1B;
#pragma unroll
    for (int r = 0; r < 16; ++r) { a0A[r]=0.f; a0B[r]=0.f; a1A[r]=0.f; a1B[r]=0.f; }

    const size_t bOff = (size_t)(4 * wv + 2 * cb) * 1024 + lane * 8;

    {
        const unsigned short* pA = wfrag + ((size_t)(s * NK16 + wv) * 2) * 512 + lane * 8;
        const unsigned short* pX = xfrag + (size_t)t * 131072 + bOff;
#pragma unroll
        for (int m = 0; m < 4; ++m) {
            short8 Ah  = LD8(pA);
            short8 Al  = LD8(pA + 512);
            short8 B0h = LD8(pX);
            short8 B0l = LD8(pX + 512);
            short8 B1h = LD8(pX + 1024);
            short8 B1l = LD8(pX + 1536);
            pA += 8192; pX += 32768;
            a0A = MFMA32(Ah, B0h, a0A);
            a1A = MFMA32(Ah, B1h, a1A);
            a0B = MFMA32(Ah, B0l, a0B);
            a1B = MFMA32(Ah, B1l, a1B);
            a0A = MFMA32(Al, B0h, a0A);
            a1A = MFMA32(Al, B1h, a1A);
        }
        const unsigned short* pH = hin + bOff;
#pragma unroll
        for (int m = 0; m < 8; ++m) {
            short8 Ah  = LD8(pA);
            short8 Al  = LD8(pA + 512);
            short8 B0h = LD8(pH);
            short8 B0l = LD8(pH + 512);
            short8 B1h = LD8(pH + 1024);
            short8 B1l = LD8(pH + 1536);
            pA += 8192; pH += 32768;
            a0A = MFMA32(Ah, B0h, a0A);
            a1A = MFMA32(Ah, B1h, a1A);
            a0B = MFMA32(Ah, B0l, a0B);
            a1B = MFMA32(Ah, B1l, a1B);
            a0A = MFMA32(Al, B0h, a0A);
            a1A = MFMA32(Al, B1h, a1A);
        }
    }

    __shared__ float part[8][32][64];
#pragma unroll
    for (int r = 0; r < 16; ++r) {
        const int lr = (r & 3) + 8 * (r >> 2) + 4 * hl;
        part[wv][lr][l31]      = a0A[r] + a0B[r];
        part[wv][lr][32 + l31] = a1A[r] + a1B[r];
    }
    __syncthreads();

    {
        const int r0 = 4 * ejl;
        float z0g = add0, z1g = add1, z2g = add2, z3g = add3;
#pragma unroll
        for (int p = 0; p < 8; ++p) {
            z0g += part[p][r0 + 0][ecl];
            z1g += part[p][r0 + 1][ecl];
            z2g += part[p][r0 + 2][ecl];
            z3g += part[p][r0 + 3][ecl];
        }
        float gg = tanh_f(z0g);
        float ig = sigmoid_f(z1g);
        float fg = sigmoid_f(z2g);
        float og = sigmoid_f(z3g);
        float cn = gg * ig + cold * fg;
        cst[ci] = cn;
        float hh = tanh_f(cn) * og;
        unsigned short hb  = f2bf(hh);
        unsigned short hlo = f2bf(hh - bf2f(hb));
        const int k16h  = s >> 1;
        const int cgg   = (colbase >> 5) + (ecl >> 5);
        const int lane8 = 32 * (s & 1) + (ecl & 31);
        unsigned short* dst = hout +
            ((size_t)((k16h * 4 + cgg) * 2) * 512) + lane8 * 8 + ejl;
        dst[0]   = hb;
        dst[512] = hlo;
        if (outf) outf[ci] = hh;
    }
}

// ---------------------------------------------------------------------------
extern "C" void kernel_launch(void* const* d_in, const int* in_sizes, int n_in,
                              void* d_out, int out_size, void* d_ws, size_t ws_size,
                              hipStream_t stream)
{
    const float* x   = (const float*)d_in[0];
    const float* c0v = (const float*)d_in[1];
    const float* h0v = (const float*)d_in[2];
    const float* Wgx = (const float*)d_in[3];
    const float* Wix = (const float*)d_in[4];
    const float* Wfx = (const float*)d_in[5];
    const float* Wox = (const float*)d_in[6];
    const float* Wgh = (const float*)d_in[7];
    const float* Wih = (const float*)d_in[8];
    const float* Wfh = (const float*)d_in[9];
    const float* Woh = (const float*)d_in[10];
    const float* bg  = (const float*)d_in[11];
    const float* bi  = (const float*)d_in[12];
    const float* bf  = (const float*)d_in[13];
    const float* bo  = (const float*)d_in[14];

    // ws layout (ushort unless noted):
    //   wfrag 25.2 MB | xfrag 67.1 MB | hbuf 32 x 0.5 MB = 16.8 MB
    //   cst 0.5 MB (f32) | flags 4 KB  => ~110 MB
    unsigned short* wfrag = (unsigned short*)d_ws;
    unsigned short* xfrag = wfrag + (size_t)128 * NK16 * 2 * 512;
    unsigned short* hbuf  = xfrag + (size_t)TSTEPS * 32 * 4 * 2 * 512;
    float* cst            = (float*)(hbuf + (size_t)HSLOTS * HSLOT);
    unsigned* flags       = (unsigned*)(cst + (size_t)HID * BATCH);

    const size_t needA = (size_t)((char*)(flags + 1024) - (char*)d_ws);
    const bool useA = (ws_size >= needA);

    float* outp = (float*)d_out;

    prep_w<<<dim3(NK16, 128), dim3(256), 0, stream>>>(Wgx, Wix, Wfx, Wox,
                                                      Wgh, Wih, Wfh, Woh, wfrag);
    prep_x<<<dim3(32, TSTEPS), dim3(256), 0, stream>>>(x, xfrag);
    prep_state<<<dim3(512), dim3(256), 0, stream>>>(c0v, h0v, cst,
                                                    hbuf + (size_t)(HSLOTS - 1) * HSLOT,
                                                    flags);

    bool done = false;
    if (useA) {
        // Cooperative launch: the runtime guarantees all 256 blocks are
        // co-resident (or returns an error instead of deadlocking).
        const unsigned short* a_wfrag = wfrag;
        const unsigned short* a_xfrag = xfrag;
        unsigned short* a_hbuf = hbuf;
        float* a_cst = cst;
        const float* a_bg = bg; const float* a_bi = bi;
        const float* a_bf = bf; const float* a_bo = bo;
        float* a_out = outp;
        unsigned* a_flags = flags;
        void* kargs[] = { (void*)&a_wfrag, (void*)&a_xfrag, (void*)&a_hbuf,
                          (void*)&a_cst, (void*)&a_bg, (void*)&a_bi,
                          (void*)&a_bf, (void*)&a_bo, (void*)&a_out,
                          (void*)&a_flags };
        hipError_t ce = hipLaunchCooperativeKernel(
            (const void*)lstm_persist, dim3(NBLK_CHUNK), dim3(512),
            kargs, 0, stream);
        done = (ce == hipSuccess);
    }

    if (!done) {
        // mode-B: per-step dispatches, h via slots 31/30, full K every step.
        unsigned short* hfA = hbuf + (size_t)(HSLOTS - 1) * HSLOT;  // initial h
        unsigned short* hfB = hbuf + (size_t)(HSLOTS - 2) * HSLOT;
        for (int t = 0; t < TSTEPS; ++t) {
            const unsigned short* hin = (t & 1) ? hfB : hfA;
            unsigned short* hout      = (t & 1) ? hfA : hfB;
            lstm_step<<<dim3(256), dim3(512), 0, stream>>>(
                wfrag, xfrag, hin, hout,
                cst, bg, bi, bf, bo,
                (t == TSTEPS - 1) ? outp : nullptr, t);
        }
    }
}